// Round 2
// baseline (444.614 us; speedup 1.0000x reference)
//
#include <hip/hip_runtime.h>

typedef unsigned short u16;
typedef short v8s __attribute__((ext_vector_type(8)));
typedef float v4f __attribute__((ext_vector_type(4)));
typedef u16 u16x8 __attribute__((ext_vector_type(8)));
typedef u16 u16x4 __attribute__((ext_vector_type(4)));

constexpr int Tn = 8192;   // tokens = B*S
constexpr int Dd = 1024;   // model dim
constexpr int Hh = 2048;   // hidden dim
constexpr int Ee = 8;      // experts
constexpr int NB = 32;     // histogram/scatter blocks
constexpr int MAXP = 17;   // ceil(max 128-row panels / 8); panels <= 128+8=136

// round-to-nearest-even f32 -> bf16 (inputs finite)
static __device__ __forceinline__ u16 f2bf(float v) {
  unsigned u = __float_as_uint(v);
  unsigned r = (u + 0x7fffu + ((u >> 16) & 1u)) >> 16;
  return (u16)r;
}

static __device__ __forceinline__ float bf2f(u16 v) {
  return __uint_as_float(((unsigned)v) << 16);
}

// async global -> LDS, 16B per lane; LDS dest = wave-uniform base + lane*16
static __device__ __forceinline__ void gload_lds16(const u16* g, u16* l) {
  __builtin_amdgcn_global_load_lds(
      (const __attribute__((address_space(1))) unsigned int*)g,
      (__attribute__((address_space(3))) unsigned int*)l, 16, 0, 0);
}

// ---------------------------------------------------------------------------
// hbuf / w2t K-PERMUTED LAYOUT:
// Within each 64-wide k-group, stored position p = l16*4 + nt holds the value
// for actual column c = nt*16 + l16  (p&3 = nt, p>>2 = l16, so actual(p) =
// (p&3)*16 + (p>>2)). gemm1's C-fragment then packs each lane's 4 outputs into
// one contiguous ushort4 store. gemm2 consumes hbuf and w2t through 64-aligned
// 16B k-chunks + an MFMA k-sum, which is order-invariant, so as long as w2t's
// Hh index is permuted IDENTICALLY (done below in transpose_cvt), gemm2's code
// is unchanged and exact.
// ---------------------------------------------------------------------------

// Fused, vectorized: W1 [E][Dd][Hh] -> w1t [E][Hh][Dd] bf16 AND
// W2 [E][Hh][Dd] -> w2t [E][Dd][Hh-PERMUTED] bf16.
// 64x64 tiles, 256 threads. float4 loads (256B rows), ushort8 16B stores.
// Blocks [0,4096) = W1, [4096,8192) = W2.
__global__ __launch_bounds__(256) void transpose_cvt_kernel(
    const float* __restrict__ W1, u16* __restrict__ w1t,
    const float* __restrict__ W2, u16* __restrict__ w2t) {
  __shared__ float tile[64][65];
  int b = blockIdx.x;
  bool isW1 = b < 4096;
  const float* in;
  u16* out;
  int R, C, cx, cy, e;
  if (isW1) {
    e = b >> 9;
    int t = b & 511;
    R = Dd; C = Hh; cx = t & 31; cy = t >> 5;       // 32 x 16 tiles
    in = W1; out = w1t;
  } else {
    int bb = b - 4096;
    e = bb >> 9;
    int t = bb & 511;
    R = Hh; C = Dd; cx = t & 15; cy = t >> 4;       // 16 x 32 tiles
    in = W2; out = w2t;
  }
  const float* ip = in + (size_t)e * Dd * Hh;
  u16* op = out + (size_t)e * Dd * Hh;
  int c0 = cx * 64, r0 = cy * 64;   // input rows [r0,r0+64), cols [c0,c0+64)
  int tid = threadIdx.x;

  // load: 4 float4 per thread; per wave-instr: 4 rows x 256B
#pragma unroll
  for (int k = 0; k < 4; ++k) {
    int f = k * 256 + tid;
    int r = f >> 4, c4 = (f & 15) * 4;
    float4 v = *reinterpret_cast<const float4*>(ip + (size_t)(r0 + r) * C + c0 + c4);
    tile[r][c4] = v.x; tile[r][c4 + 1] = v.y; tile[r][c4 + 2] = v.z; tile[r][c4 + 3] = v.w;
  }
  __syncthreads();

  // store: out element (c, r') = in(r, c); out row = input col (oc),
  // out col chunk j covers stored idx [8j, 8j+8) -> one 16B store.
  int j = tid & 7;
#pragma unroll
  for (int rr = 0; rr < 2; ++rr) {
    int oc = (tid >> 3) + rr * 32;
    u16x8 o;
    if (isW1) {
#pragma unroll
      for (int q = 0; q < 8; ++q) o[q] = f2bf(tile[j * 8 + q][oc]);
    } else {
      // permuted: stored p holds actual input-row (p&3)*16 + (p>>2)
#pragma unroll
      for (int q = 0; q < 8; ++q) {
        int p = j * 8 + q;
        int src = (p & 3) * 16 + (p >> 2);
        o[q] = f2bf(tile[src][oc]);
      }
    }
    *reinterpret_cast<u16x8*>(op + (size_t)(c0 + oc) * R + r0 + j * 8) = o;
  }
}

// one wave per token; fused x->bf16 conversion; no global atomics
__global__ __launch_bounds__(256) void gating_kernel(
    const float* __restrict__ x, const float* __restrict__ Wg, const float* __restrict__ bg,
    int* __restrict__ topki, float* __restrict__ topkw, u16* __restrict__ xb) {
  int lane = threadIdx.x & 63;
  int t = blockIdx.x * 4 + (threadIdx.x >> 6);
  const float4* xr = reinterpret_cast<const float4*>(x + (size_t)t * Dd);
  float acc[8] = {0.f, 0.f, 0.f, 0.f, 0.f, 0.f, 0.f, 0.f};
#pragma unroll
  for (int it = 0; it < 4; ++it) {
    float4 xv = xr[it * 64 + lane];
    int r = it * 256 + lane * 4;
    ushort4 o;
    o.x = f2bf(xv.x); o.y = f2bf(xv.y); o.z = f2bf(xv.z); o.w = f2bf(xv.w);
    *reinterpret_cast<ushort4*>(xb + (size_t)t * Dd + r) = o;
    const float4* wr = reinterpret_cast<const float4*>(Wg + (size_t)r * 8);
    float xs[4] = {xv.x, xv.y, xv.z, xv.w};
#pragma unroll
    for (int q = 0; q < 4; ++q) {
      float4 a = wr[q * 2], b = wr[q * 2 + 1];
      acc[0] += xs[q] * a.x; acc[1] += xs[q] * a.y; acc[2] += xs[q] * a.z; acc[3] += xs[q] * a.w;
      acc[4] += xs[q] * b.x; acc[5] += xs[q] * b.y; acc[6] += xs[q] * b.z; acc[7] += xs[q] * b.w;
    }
  }
#pragma unroll
  for (int e = 0; e < 8; ++e) {
#pragma unroll
    for (int off = 32; off > 0; off >>= 1) acc[e] += __shfl_xor(acc[e], off, 64);
  }
  if (lane == 0) {
    float l[8];
    float mx = -1e30f;
#pragma unroll
    for (int e = 0; e < 8; ++e) { l[e] = acc[e] + bg[e]; mx = fmaxf(mx, l[e]); }
    int i0 = 0;
#pragma unroll
    for (int e = 1; e < 8; ++e) if (l[e] > l[i0]) i0 = e;
    int i1 = (i0 == 0) ? 1 : 0;
#pragma unroll
    for (int e = 0; e < 8; ++e) if (e != i0 && l[e] > l[i1]) i1 = e;
    float e0 = __expf(l[i0] - mx), e1 = __expf(l[i1] - mx);
    float inv = 1.0f / (e0 + e1);
    topki[2 * t] = i0; topki[2 * t + 1] = i1;
    topkw[2 * t] = e0 * inv; topkw[2 * t + 1] = e1 * inv;
  }
}

// per-block expert histogram via LDS atomics; 8 global stores per block
__global__ __launch_bounds__(256) void hist_kernel(const int* __restrict__ topki,
                                                   int* __restrict__ blockcnt) {
  __shared__ int bins[8];
  int tid = threadIdx.x, b = blockIdx.x;
  if (tid < 8) bins[tid] = 0;
  __syncthreads();
  atomicAdd(&bins[topki[b * 512 + tid]], 1);
  atomicAdd(&bins[topki[b * 512 + 256 + tid]], 1);
  __syncthreads();
  if (tid < 8) blockcnt[b * 8 + tid] = bins[tid];
}

// prefix sums + XCD-pinned 128-row panel work-list
__global__ void prefix_kernel(const int* __restrict__ blockcnt, int* __restrict__ offs,
                              int* __restrict__ blockstart,
                              int* __restrict__ panelE, int* __restrict__ panelB,
                              int* __restrict__ nPanels) {
  __shared__ int tmp[8][NB];
  __shared__ int tot[8];
  int tid = threadIdx.x;
  if (tid < 8) {
    int s = 0;
    for (int b = 0; b < NB; ++b) { tmp[tid][b] = s; s += blockcnt[b * 8 + tid]; }
    tot[tid] = s;
  }
  __syncthreads();
  if (tid == 0) {
    int o = 0;
    for (int e = 0; e < 8; ++e) { offs[e] = o; o += tot[e]; }
    offs[8] = o;
    int np = 0;
    for (int e = 0; e < 8; ++e) {
      for (int m0 = 0; m0 < tot[e]; m0 += 128) {
        panelE[np] = e;
        panelB[np] = offs[e] + m0;
        ++np;
      }
    }
    *nPanels = np;
  }
  __syncthreads();
  if (tid < 8)
    for (int b = 0; b < NB; ++b) blockstart[b * 8 + tid] = offs[tid] + tmp[tid][b];
}

// slot assignment with LDS-local ranks; zero global atomics
__global__ __launch_bounds__(256) void scatter_kernel(
    const int* __restrict__ topki, const int* __restrict__ blockstart,
    int* __restrict__ rows, int* __restrict__ slotmap) {
  __shared__ int lbins[8];
  int tid = threadIdx.x, b = blockIdx.x;
  if (tid < 8) lbins[tid] = blockstart[b * 8 + tid];
  __syncthreads();
#pragma unroll
  for (int j = 0; j < 2; ++j) {
    int idx = b * 512 + j * 256 + tid;
    int e = topki[idx];
    int slot = atomicAdd(&lbins[e], 1);
    rows[slot] = idx >> 1;
    slotmap[idx] = slot;
  }
}

// ---- GEMM cores: 128x128 tile, BK=64, XOR-swizzled LDS ----
// R2 change: 8 waves (512 thr) per block, per-wave output 32x128 (acc 2x4 =
// 32 AGPR). Unified regs ~100 -> 2 blocks/CU * 8 waves = 16 waves/CU (~50%
// occupancy) vs 4-wave version's ~12. More TLP to cover the vmcnt(0) barrier
// drain; schedule/layout/swizzle unchanged.

// GEMM1: h[slot][P(n)] = gelu( x[rows[slot]] @ W1[e] + b1[e] )  (k-permuted store)
__global__ __launch_bounds__(512, 4) void gemm1_kernel(
    const u16* __restrict__ xb, const u16* __restrict__ w1t, const float* __restrict__ b1,
    const int* __restrict__ offs, const int* __restrict__ rows,
    const int* __restrict__ panelE, const int* __restrict__ panelB,
    const int* __restrict__ nPanels, u16* __restrict__ hbuf) {
  const int bid = blockIdx.x;
  const int xcd = bid & 7;
  const int q = bid >> 3;
  const int n = q & 15;               // Hh/128 = 16 n-blocks
  const int pi = (q >> 4) * 8 + xcd;
  if (pi >= *nPanels) return;
  const int e = panelE[pi];
  const int sbase = panelB[pi];
  const int lim = offs[e + 1];
  const int n0 = n * 128;

  __shared__ u16 As[128 * 64];        // 16 KB
  __shared__ u16 Bs[128 * 64];        // 16 KB

  const int tid = threadIdx.x;
  const int lane = tid & 63;
  const int wid = tid >> 6;           // 0..7
  const int wm = (wid >> 1) * 32;     // 4 M-slices of 32 rows
  const int wn = (wid & 1) * 64;      // 2 N-slices of 64 cols
  const int l16 = lane & 15;
  const int quad = lane >> 4;
  const int swz8 = (l16 & 7) * 8;     // read-side XOR mask (elems)

  const u16* aga[2];
  const u16* bga[2];
  u16* alds[2];
  u16* blds[2];
  const int lr = lane >> 3;                 // row within 8-row chunk
  const int g = (lane & 7) ^ (lr & 7);      // staged global k-chunk (XOR swizzle)
  const int kcol = g * 8;
#pragma unroll
  for (int j = 0; j < 2; ++j) {
    int chunk = wid * 2 + j;                // 0..15 covers rows [chunk*8, chunk*8+8)
    int rowl = chunk * 8 + lr;
    int slot = sbase + rowl;
    if (slot >= lim) slot = sbase;
    aga[j] = xb + (size_t)rows[slot] * Dd + kcol;
    bga[j] = w1t + ((size_t)e * Hh + n0 + rowl) * Dd + kcol;
    alds[j] = As + chunk * 512;             // 1 KB per wave-instruction
    blds[j] = Bs + chunk * 512;
  }

  v4f acc[2][4];
#pragma unroll
  for (int i = 0; i < 2; ++i)
#pragma unroll
    for (int j = 0; j < 4; ++j) acc[i][j] = {0.f, 0.f, 0.f, 0.f};

  int rowAoff[2], rowBoff[4];
#pragma unroll
  for (int t_ = 0; t_ < 2; ++t_) rowAoff[t_] = (wm + t_ * 16 + l16) * 64;
#pragma unroll
  for (int t_ = 0; t_ < 4; ++t_) rowBoff[t_] = (wn + t_ * 16 + l16) * 64;

  for (int k0 = 0; k0 < Dd; k0 += 64) {
    __syncthreads();
#pragma unroll
    for (int j = 0; j < 2; ++j) gload_lds16(aga[j] + k0, alds[j]);
#pragma unroll
    for (int j = 0; j < 2; ++j) gload_lds16(bga[j] + k0, blds[j]);
    __syncthreads();

#pragma unroll
    for (int s = 0; s < 2; ++s) {
      int coff = ((s * 4 + quad) * 8) ^ swz8;
      v8s a[2], b[4];
#pragma unroll
      for (int mt = 0; mt < 2; ++mt)
        a[mt] = *reinterpret_cast<const v8s*>(&As[rowAoff[mt] + coff]);
#pragma unroll
      for (int nt = 0; nt < 4; ++nt)
        b[nt] = *reinterpret_cast<const v8s*>(&Bs[rowBoff[nt] + coff]);
#pragma unroll
      for (int mt = 0; mt < 2; ++mt)
#pragma unroll
        for (int nt = 0; nt < 4; ++nt)
          acc[mt][nt] = __builtin_amdgcn_mfma_f32_16x16x32_bf16(a[mt], b[nt], acc[mt][nt], 0, 0, 0);
    }
  }

  // epilogue: bias + gelu, PACKED 8B stores into k-permuted hbuf.
  // lane's 4 outputs (cols wn+nt*16+l16) land at stored idx l16*4+nt -> contiguous.
  float b1v[4];
  const int ngbase = n0 + wn;           // 64-aligned group base
#pragma unroll
  for (int nt = 0; nt < 4; ++nt) b1v[nt] = b1[(size_t)e * Hh + ngbase + nt * 16 + l16];
#pragma unroll
  for (int mt = 0; mt < 2; ++mt) {
#pragma unroll
    for (int i = 0; i < 4; ++i) {
      int m = wm + mt * 16 + quad * 4 + i;
      if (sbase + m < lim) {
        u16x4 o;
#pragma unroll
        for (int nt = 0; nt < 4; ++nt) {
          float v = acc[mt][nt][i] + b1v[nt];
          float s = 1.0f / (1.0f + __expf(-1.5957691216057308f * (v + 0.044715f * v * v * v)));
          o[nt] = f2bf(v * s);
        }
        *reinterpret_cast<u16x4*>(hbuf + (size_t)(sbase + m) * Hh + ngbase + l16 * 4) = o;
      }
    }
  }
}

// GEMM2: ybuf[slot][n] = h[slot] @ W2[e] + b2[e]
// (hbuf and w2t share the same k-permutation within 64-groups; the MFMA k-sum
// is order-invariant, so this kernel is layout-agnostic to the permute.)
__global__ __launch_bounds__(512, 4) void gemm2_kernel(
    const u16* __restrict__ hbuf, const u16* __restrict__ w2t, const float* __restrict__ b2,
    const int* __restrict__ offs,
    const int* __restrict__ panelE, const int* __restrict__ panelB,
    const int* __restrict__ nPanels, u16* __restrict__ ybuf) {
  const int bid = blockIdx.x;
  const int xcd = bid & 7;
  const int q = bid >> 3;
  const int n = q & 7;                // Dd/128 = 8 n-blocks
  const int pi = (q >> 3) * 8 + xcd;
  if (pi >= *nPanels) return;
  const int e = panelE[pi];
  const int sbase = panelB[pi];
  const int lim = offs[e + 1];
  const int n0 = n * 128;

  __shared__ u16 As[128 * 64];
  __shared__ u16 Bs[128 * 64];

  const int tid = threadIdx.x;
  const int lane = tid & 63;
  const int wid = tid >> 6;
  const int wm = (wid >> 1) * 32;
  const int wn = (wid & 1) * 64;
  const int l16 = lane & 15;
  const int quad = lane >> 4;
  const int swz8 = (l16 & 7) * 8;

  const u16* aga[2];
  const u16* bga[2];
  u16* alds[2];
  u16* blds[2];
  const int lr = lane >> 3;
  const int g = (lane & 7) ^ (lr & 7);
  const int kcol = g * 8;
#pragma unroll
  for (int j = 0; j < 2; ++j) {
    int chunk = wid * 2 + j;
    int rowl = chunk * 8 + lr;
    int slot = sbase + rowl;
    if (slot >= lim) slot = sbase;
    aga[j] = hbuf + (size_t)slot * Hh + kcol;
    bga[j] = w2t + ((size_t)e * Dd + n0 + rowl) * Hh + kcol;
    alds[j] = As + chunk * 512;
    blds[j] = Bs + chunk * 512;
  }

  v4f acc[2][4];
#pragma unroll
  for (int i = 0; i < 2; ++i)
#pragma unroll
    for (int j = 0; j < 4; ++j) acc[i][j] = {0.f, 0.f, 0.f, 0.f};

  int rowAoff[2], rowBoff[4];
#pragma unroll
  for (int t_ = 0; t_ < 2; ++t_) rowAoff[t_] = (wm + t_ * 16 + l16) * 64;
#pragma unroll
  for (int t_ = 0; t_ < 4; ++t_) rowBoff[t_] = (wn + t_ * 16 + l16) * 64;

  for (int k0 = 0; k0 < Hh; k0 += 64) {
    __syncthreads();
#pragma unroll
    for (int j = 0; j < 2; ++j) gload_lds16(aga[j] + k0, alds[j]);
#pragma unroll
    for (int j = 0; j < 2; ++j) gload_lds16(bga[j] + k0, blds[j]);
    __syncthreads();

#pragma unroll
    for (int s = 0; s < 2; ++s) {
      int coff = ((s * 4 + quad) * 8) ^ swz8;
      v8s a[2], b[4];
#pragma unroll
      for (int mt = 0; mt < 2; ++mt)
        a[mt] = *reinterpret_cast<const v8s*>(&As[rowAoff[mt] + coff]);
#pragma unroll
      for (int nt = 0; nt < 4; ++nt)
        b[nt] = *reinterpret_cast<const v8s*>(&Bs[rowBoff[nt] + coff]);
#pragma unroll
      for (int mt = 0; mt < 2; ++mt)
#pragma unroll
        for (int nt = 0; nt < 4; ++nt)
          acc[mt][nt] = __builtin_amdgcn_mfma_f32_16x16x32_bf16(a[mt], b[nt], acc[mt][nt], 0, 0, 0);
    }
  }

  float b2v[4];
  int ng[4];
#pragma unroll
  for (int nt = 0; nt < 4; ++nt) {
    ng[nt] = n0 + wn + nt * 16 + l16;
    b2v[nt] = b2[(size_t)e * Dd + ng[nt]];
  }
#pragma unroll
  for (int mt = 0; mt < 2; ++mt) {
#pragma unroll
    for (int i = 0; i < 4; ++i) {
      int m = wm + mt * 16 + quad * 4 + i;
      if (sbase + m < lim) {
        size_t rowbase = (size_t)(sbase + m) * Dd;
#pragma unroll
        for (int nt = 0; nt < 4; ++nt)
          ybuf[rowbase + ng[nt]] = f2bf(acc[mt][nt][i] + b2v[nt]);
      }
    }
  }
}

// out[t] = w0 * y[slot0] + w1 * y[slot1]
__global__ __launch_bounds__(256) void combine_kernel(
    const u16* __restrict__ ybuf, const int* __restrict__ slotmap,
    const float* __restrict__ topkw, float* __restrict__ out) {
  int idx = blockIdx.x * 256 + threadIdx.x;
  int t = idx >> 7;
  int d0 = (idx & 127) * 8;
  int s0 = slotmap[2 * t], s1 = slotmap[2 * t + 1];
  float w0 = topkw[2 * t], w1 = topkw[2 * t + 1];
  uint4 ya = *reinterpret_cast<const uint4*>(ybuf + (size_t)s0 * Dd + d0);
  uint4 yb = *reinterpret_cast<const uint4*>(ybuf + (size_t)s1 * Dd + d0);
  float r[8];
  const unsigned* pa = &ya.x;
  const unsigned* pb = &yb.x;
#pragma unroll
  for (int j = 0; j < 4; ++j) {
    unsigned a = pa[j], b = pb[j];
    r[2 * j]     = w0 * bf2f((u16)(a & 0xffff)) + w1 * bf2f((u16)(b & 0xffff));
    r[2 * j + 1] = w0 * bf2f((u16)(a >> 16))    + w1 * bf2f((u16)(b >> 16));
  }
  float4* op = reinterpret_cast<float4*>(out + (size_t)t * Dd + d0);
  op[0] = make_float4(r[0], r[1], r[2], r[3]);
  op[1] = make_float4(r[4], r[5], r[6], r[7]);
}

extern "C" void kernel_launch(void* const* d_in, const int* in_sizes, int n_in,
                              void* d_out, int out_size, void* d_ws, size_t ws_size,
                              hipStream_t stream) {
  const float* x  = (const float*)d_in[0];
  const float* Wg = (const float*)d_in[2];
  const float* bg = (const float*)d_in[3];
  const float* W1 = (const float*)d_in[4];
  const float* b1 = (const float*)d_in[5];
  const float* W2 = (const float*)d_in[6];
  const float* b2 = (const float*)d_in[7];
  float* out = (float*)d_out;

  char* p = (char*)d_ws;
  auto take = [&](size_t bytes) {
    char* q = p;
    p += (bytes + 255) & ~(size_t)255;
    return q;
  };
  int*   offs       = (int*)take(64);
  int*   blockcnt   = (int*)take((size_t)NB * 8 * sizeof(int));
  int*   blockstart = (int*)take((size_t)NB * 8 * sizeof(int));
  int*   panelE     = (int*)take(1024);
  int*   panelB     = (int*)take(1024);
  int*   nPanels    = (int*)take(256);
  int*   topki      = (int*)take((size_t)Tn * 2 * sizeof(int));
  float* topkw      = (float*)take((size_t)Tn * 2 * sizeof(float));
  int*   rows       = (int*)take((size_t)Tn * 2 * sizeof(int));
  int*   slotmap    = (int*)take((size_t)Tn * 2 * sizeof(int));
  u16*   xb         = (u16*)take((size_t)Tn * Dd * 2);
  u16*   w1t        = (u16*)take((size_t)Ee * Dd * Hh * 2);
  u16*   w2t        = (u16*)take((size_t)Ee * Dd * Hh * 2);
  u16*   hbuf       = (u16*)take((size_t)Tn * 2 * Hh * 2);
  u16*   ybuf       = (u16*)take((size_t)Tn * 2 * Dd * 2);

  transpose_cvt_kernel<<<8192, 256, 0, stream>>>(W1, w1t, W2, w2t);
  gating_kernel<<<Tn / 4, 256, 0, stream>>>(x, Wg, bg, topki, topkw, xb);
  hist_kernel<<<NB, 256, 0, stream>>>(topki, blockcnt);
  prefix_kernel<<<1, 64, 0, stream>>>(blockcnt, offs, blockstart, panelE, panelB, nPanels);
  scatter_kernel<<<NB, 256, 0, stream>>>(topki, blockstart, rows, slotmap);
  gemm1_kernel<<<8 * 16 * MAXP, 512, 0, stream>>>(xb, w1t, b1, offs, rows,
                                                  panelE, panelB, nPanels, hbuf);
  gemm2_kernel<<<8 * 8 * MAXP, 512, 0, stream>>>(hbuf, w2t, b2, offs,
                                                 panelE, panelB, nPanels, ybuf);
  combine_kernel<<<(Tn * Dd / 8) / 256, 256, 0, stream>>>(ybuf, slotmap, topkw, out);
}

// Round 3
// 428.611 us; speedup vs baseline: 1.0373x; 1.0373x over previous
//
#include <hip/hip_runtime.h>

typedef unsigned short u16;
typedef short v8s __attribute__((ext_vector_type(8)));
typedef float v4f __attribute__((ext_vector_type(4)));
typedef u16 u16x8 __attribute__((ext_vector_type(8)));
typedef u16 u16x4 __attribute__((ext_vector_type(4)));

constexpr int Tn = 8192;   // tokens = B*S
constexpr int Dd = 1024;   // model dim
constexpr int Hh = 2048;   // hidden dim
constexpr int Ee = 8;      // experts
constexpr int MAXP = 17;   // ceil(max 128-row panels / 8); panels <= 128+8=136

// round-to-nearest-even f32 -> bf16 (inputs finite)
static __device__ __forceinline__ u16 f2bf(float v) {
  unsigned u = __float_as_uint(v);
  unsigned r = (u + 0x7fffu + ((u >> 16) & 1u)) >> 16;
  return (u16)r;
}

static __device__ __forceinline__ float bf2f(u16 v) {
  return __uint_as_float(((unsigned)v) << 16);
}

// async global -> LDS, 16B per lane; LDS dest = wave-uniform base + lane*16
static __device__ __forceinline__ void gload_lds16(const u16* g, u16* l) {
  __builtin_amdgcn_global_load_lds(
      (const __attribute__((address_space(1))) unsigned int*)g,
      (__attribute__((address_space(3))) unsigned int*)l, 16, 0, 0);
}

// ---------------------------------------------------------------------------
// hbuf / w2t K-PERMUTED LAYOUT:
// Within each 64-wide k-group, stored position p = l16*4 + nt holds the value
// for actual column c = nt*16 + l16. gemm1's C-fragment packs each lane's 4
// outputs into one contiguous ushort4 store; gemm2 consumes hbuf/w2t through
// 64-aligned 16B k-chunks + an order-invariant MFMA k-sum, so w2t's Hh index
// is permuted identically at transpose time and gemm2 is unchanged.
// ---------------------------------------------------------------------------

// PREP (fused): blocks [0,2048) = gating (+x->bf16), blocks [2048,10240) =
// W1/W2 transpose+cvt. Gating blocks first so they fill early and hide under
// the transpose; one launch instead of two.
__global__ __launch_bounds__(256) void prep_kernel(
    const float* __restrict__ x, const float* __restrict__ Wg, const float* __restrict__ bg,
    int* __restrict__ topki, float* __restrict__ topkw, u16* __restrict__ xb,
    const float* __restrict__ W1, u16* __restrict__ w1t,
    const float* __restrict__ W2, u16* __restrict__ w2t) {
  __shared__ float tile[64][65];
  int blk = blockIdx.x;

  if (blk < 2048) {
    // ---------------- gating: one wave per token ----------------
    int lane = threadIdx.x & 63;
    int t = blk * 4 + (threadIdx.x >> 6);
    const float4* xr = reinterpret_cast<const float4*>(x + (size_t)t * Dd);
    float acc[8] = {0.f, 0.f, 0.f, 0.f, 0.f, 0.f, 0.f, 0.f};
#pragma unroll
    for (int it = 0; it < 4; ++it) {
      float4 xv = xr[it * 64 + lane];
      int r = it * 256 + lane * 4;
      ushort4 o;
      o.x = f2bf(xv.x); o.y = f2bf(xv.y); o.z = f2bf(xv.z); o.w = f2bf(xv.w);
      *reinterpret_cast<ushort4*>(xb + (size_t)t * Dd + r) = o;
      const float4* wr = reinterpret_cast<const float4*>(Wg + (size_t)r * 8);
      float xs[4] = {xv.x, xv.y, xv.z, xv.w};
#pragma unroll
      for (int q = 0; q < 4; ++q) {
        float4 a = wr[q * 2], b = wr[q * 2 + 1];
        acc[0] += xs[q] * a.x; acc[1] += xs[q] * a.y; acc[2] += xs[q] * a.z; acc[3] += xs[q] * a.w;
        acc[4] += xs[q] * b.x; acc[5] += xs[q] * b.y; acc[6] += xs[q] * b.z; acc[7] += xs[q] * b.w;
      }
    }
#pragma unroll
    for (int e = 0; e < 8; ++e) {
#pragma unroll
      for (int off = 32; off > 0; off >>= 1) acc[e] += __shfl_xor(acc[e], off, 64);
    }
    if (lane == 0) {
      float l[8];
      float mx = -1e30f;
#pragma unroll
      for (int e = 0; e < 8; ++e) { l[e] = acc[e] + bg[e]; mx = fmaxf(mx, l[e]); }
      int i0 = 0;
#pragma unroll
      for (int e = 1; e < 8; ++e) if (l[e] > l[i0]) i0 = e;
      int i1 = (i0 == 0) ? 1 : 0;
#pragma unroll
      for (int e = 0; e < 8; ++e) if (e != i0 && l[e] > l[i1]) i1 = e;
      float e0 = __expf(l[i0] - mx), e1 = __expf(l[i1] - mx);
      float inv = 1.0f / (e0 + e1);
      topki[2 * t] = i0; topki[2 * t + 1] = i1;
      topkw[2 * t] = e0 * inv; topkw[2 * t + 1] = e1 * inv;
    }
    return;
  }

  // ---------------- transpose + cvt: 64x64 tiles ----------------
  int b = blk - 2048;
  bool isW1 = b < 4096;
  const float* in;
  u16* out;
  int R, C, cx, cy, e;
  if (isW1) {
    e = b >> 9;
    int t = b & 511;
    R = Dd; C = Hh; cx = t & 31; cy = t >> 5;       // 32 x 16 tiles
    in = W1; out = w1t;
  } else {
    int bb = b - 4096;
    e = bb >> 9;
    int t = bb & 511;
    R = Hh; C = Dd; cx = t & 15; cy = t >> 4;       // 16 x 32 tiles
    in = W2; out = w2t;
  }
  const float* ip = in + (size_t)e * Dd * Hh;
  u16* op = out + (size_t)e * Dd * Hh;
  int c0 = cx * 64, r0 = cy * 64;   // input rows [r0,r0+64), cols [c0,c0+64)
  int tid = threadIdx.x;

  // load: 4 float4 per thread; per wave-instr: 4 rows x 256B
#pragma unroll
  for (int k = 0; k < 4; ++k) {
    int f = k * 256 + tid;
    int r = f >> 4, c4 = (f & 15) * 4;
    float4 v = *reinterpret_cast<const float4*>(ip + (size_t)(r0 + r) * C + c0 + c4);
    tile[r][c4] = v.x; tile[r][c4 + 1] = v.y; tile[r][c4 + 2] = v.z; tile[r][c4 + 3] = v.w;
  }
  __syncthreads();

  // store: out element (c, r') = in(r, c); one 16B store per chunk.
  int j = tid & 7;
#pragma unroll
  for (int rr = 0; rr < 2; ++rr) {
    int oc = (tid >> 3) + rr * 32;
    u16x8 o;
    if (isW1) {
#pragma unroll
      for (int q = 0; q < 8; ++q) o[q] = f2bf(tile[j * 8 + q][oc]);
    } else {
      // permuted: stored p holds actual input-row (p&3)*16 + (p>>2)
#pragma unroll
      for (int q = 0; q < 8; ++q) {
        int p = j * 8 + q;
        int src = (p & 3) * 16 + (p >> 2);
        o[q] = f2bf(tile[src][oc]);
      }
    }
    *reinterpret_cast<u16x8*>(op + (size_t)(c0 + oc) * R + r0 + j * 8) = o;
  }
}

// SORT (fused hist+prefix+scatter): ONE block, 512 threads, no atomics.
// Phase A: per-thread 8-bin counts of its 32 assignments (static accumulate).
// Phase B: per-expert exclusive scan over 512 threads (one wave per expert),
//          totals -> expert offsets + 128-row panel work list.
// Phase C: per-thread slot assignment via exclusive LDS cursors.
// Slot order within an expert is a permutation of the old scheme -> output
// invariant (per-row math identical, combine gathers via slotmap).
__global__ __launch_bounds__(512) void sort_kernel(
    const int* __restrict__ topki,
    int* __restrict__ offs, int* __restrict__ rows, int* __restrict__ slotmap,
    int* __restrict__ panelE, int* __restrict__ panelB, int* __restrict__ nPanels) {
  __shared__ int scan[8][512];   // counts -> exclusive within-expert prefixes
  __shared__ int tot_l[8];
  __shared__ int offs_l[9];
  const int tt = threadIdx.x;    // 0..511
  const int base = tt * 32;      // 512*32 = 16384 = Tn*2 entries

  // phase A
  int ev[32];
  int cnt[8] = {0, 0, 0, 0, 0, 0, 0, 0};
#pragma unroll
  for (int jj = 0; jj < 32; ++jj) {
    int e = topki[base + jj];
    ev[jj] = e;
#pragma unroll
    for (int q = 0; q < 8; ++q) cnt[q] += (e == q) ? 1 : 0;
  }
#pragma unroll
  for (int q = 0; q < 8; ++q) scan[q][tt] = cnt[q];
  __syncthreads();

  // phase B: wave w scans expert row w
  {
    int w = tt >> 6, l = tt & 63;
    int v[8];
    int s = 0;
#pragma unroll
    for (int jj = 0; jj < 8; ++jj) { v[jj] = scan[w][l * 8 + jj]; s += v[jj]; }
    int si = s;
#pragma unroll
    for (int off = 1; off < 64; off <<= 1) {
      int o = __shfl_up(si, off, 64);
      if (l >= off) si += o;
    }
    int run = si - s;  // exclusive base for this lane's 8 threads
#pragma unroll
    for (int jj = 0; jj < 8; ++jj) { scan[w][l * 8 + jj] = run; run += v[jj]; }
    if (l == 63) tot_l[w] = si;
  }
  __syncthreads();

  if (tt == 0) {
    int o = 0;
#pragma unroll
    for (int e = 0; e < 8; ++e) { offs_l[e] = o; o += tot_l[e]; }
    offs_l[8] = o;
#pragma unroll
    for (int e = 0; e < 9; ++e) offs[e] = offs_l[e];
    int np = 0;
    for (int e = 0; e < 8; ++e) {
      for (int m0 = 0; m0 < tot_l[e]; m0 += 128) {
        panelE[np] = e;
        panelB[np] = offs_l[e] + m0;
        ++np;
      }
    }
    *nPanels = np;
  }
  __syncthreads();

  // phase C: slot assignment (scan[e][tt] is this thread's private cursor)
#pragma unroll
  for (int jj = 0; jj < 32; ++jj) {
    int e = ev[jj];
    int idx = base + jj;
    int slot = scan[e][tt]++;        // exclusive owner; 2-way bank alias only
    slot += offs_l[e];
    rows[slot] = idx >> 1;
    slotmap[idx] = slot;
  }
}

// ---- GEMM cores: 128x128 tile, BK=64, XOR-swizzled LDS (R1 config: proven) ----
// R2 post-mortem: 8-wave/512-thr split raised occupancy 27->38% but CUT
// MfmaUtil 30->25% and cost +17% time — in this lockstep 2-barrier structure
// per-wave compute depth between barriers matters more than wave count.
// (256,2) / 4 waves / acc 4x4 is the structural optimum for this geometry.

// GEMM1: h[slot][P(n)] = gelu( x[rows[slot]] @ W1[e] + b1[e] )  (k-permuted store)
__global__ __launch_bounds__(256, 2) void gemm1_kernel(
    const u16* __restrict__ xb, const u16* __restrict__ w1t, const float* __restrict__ b1,
    const int* __restrict__ offs, const int* __restrict__ rows,
    const int* __restrict__ panelE, const int* __restrict__ panelB,
    const int* __restrict__ nPanels, u16* __restrict__ hbuf) {
  const int bid = blockIdx.x;
  const int xcd = bid & 7;
  const int q = bid >> 3;
  const int n = q & 15;               // Hh/128 = 16 n-blocks
  const int pi = (q >> 4) * 8 + xcd;
  if (pi >= *nPanels) return;
  const int e = panelE[pi];
  const int sbase = panelB[pi];
  const int lim = offs[e + 1];
  const int n0 = n * 128;

  __shared__ u16 As[128 * 64];        // 16 KB
  __shared__ u16 Bs[128 * 64];        // 16 KB

  const int tid = threadIdx.x;
  const int lane = tid & 63;
  const int wid = tid >> 6;
  const int wm = (wid >> 1) * 64;
  const int wn = (wid & 1) * 64;
  const int l16 = lane & 15;
  const int quad = lane >> 4;
  const int swz8 = (l16 & 7) * 8;     // read-side XOR mask (elems)

  const u16* aga[4];
  const u16* bga[4];
  u16* alds[4];
  u16* blds[4];
  const int lr = lane >> 3;                 // row within 8-row chunk
  const int g = (lane & 7) ^ (lr & 7);      // staged global k-chunk (XOR swizzle)
  const int kcol = g * 8;
#pragma unroll
  for (int j = 0; j < 4; ++j) {
    int chunk = wid * 4 + j;                // 0..15 covers rows [chunk*8, chunk*8+8)
    int rowl = chunk * 8 + lr;
    int slot = sbase + rowl;
    if (slot >= lim) slot = sbase;
    aga[j] = xb + (size_t)rows[slot] * Dd + kcol;
    bga[j] = w1t + ((size_t)e * Hh + n0 + rowl) * Dd + kcol;
    alds[j] = As + chunk * 512;             // 1 KB per wave-instruction
    blds[j] = Bs + chunk * 512;
  }

  v4f acc[4][4];
#pragma unroll
  for (int i = 0; i < 4; ++i)
#pragma unroll
    for (int j = 0; j < 4; ++j) acc[i][j] = {0.f, 0.f, 0.f, 0.f};

  int rowAoff[4], rowBoff[4];
#pragma unroll
  for (int t_ = 0; t_ < 4; ++t_) {
    rowAoff[t_] = (wm + t_ * 16 + l16) * 64;
    rowBoff[t_] = (wn + t_ * 16 + l16) * 64;
  }

  for (int k0 = 0; k0 < Dd; k0 += 64) {
    __syncthreads();
#pragma unroll
    for (int j = 0; j < 4; ++j) gload_lds16(aga[j] + k0, alds[j]);
#pragma unroll
    for (int j = 0; j < 4; ++j) gload_lds16(bga[j] + k0, blds[j]);
    __syncthreads();

#pragma unroll
    for (int s = 0; s < 2; ++s) {
      int coff = ((s * 4 + quad) * 8) ^ swz8;
      v8s a[4], b[4];
#pragma unroll
      for (int mt = 0; mt < 4; ++mt)
        a[mt] = *reinterpret_cast<const v8s*>(&As[rowAoff[mt] + coff]);
#pragma unroll
      for (int nt = 0; nt < 4; ++nt)
        b[nt] = *reinterpret_cast<const v8s*>(&Bs[rowBoff[nt] + coff]);
#pragma unroll
      for (int mt = 0; mt < 4; ++mt)
#pragma unroll
        for (int nt = 0; nt < 4; ++nt)
          acc[mt][nt] = __builtin_amdgcn_mfma_f32_16x16x32_bf16(a[mt], b[nt], acc[mt][nt], 0, 0, 0);
    }
  }

  // epilogue: bias + gelu, PACKED 8B stores into k-permuted hbuf.
  float b1v[4];
  const int ngbase = n0 + wn;           // 64-aligned group base
#pragma unroll
  for (int nt = 0; nt < 4; ++nt) b1v[nt] = b1[(size_t)e * Hh + ngbase + nt * 16 + l16];
#pragma unroll
  for (int mt = 0; mt < 4; ++mt) {
#pragma unroll
    for (int i = 0; i < 4; ++i) {
      int m = wm + mt * 16 + quad * 4 + i;
      if (sbase + m < lim) {
        u16x4 o;
#pragma unroll
        for (int nt = 0; nt < 4; ++nt) {
          float v = acc[mt][nt][i] + b1v[nt];
          float s = 1.0f / (1.0f + __expf(-1.5957691216057308f * (v + 0.044715f * v * v * v)));
          o[nt] = f2bf(v * s);
        }
        *reinterpret_cast<u16x4*>(hbuf + (size_t)(sbase + m) * Hh + ngbase + l16 * 4) = o;
      }
    }
  }
}

// GEMM2: ybuf[slot][n] = h[slot] @ W2[e] + b2[e]
__global__ __launch_bounds__(256, 2) void gemm2_kernel(
    const u16* __restrict__ hbuf, const u16* __restrict__ w2t, const float* __restrict__ b2,
    const int* __restrict__ offs,
    const int* __restrict__ panelE, const int* __restrict__ panelB,
    const int* __restrict__ nPanels, u16* __restrict__ ybuf) {
  const int bid = blockIdx.x;
  const int xcd = bid & 7;
  const int q = bid >> 3;
  const int n = q & 7;                // Dd/128 = 8 n-blocks
  const int pi = (q >> 3) * 8 + xcd;
  if (pi >= *nPanels) return;
  const int e = panelE[pi];
  const int sbase = panelB[pi];
  const int lim = offs[e + 1];
  const int n0 = n * 128;

  __shared__ u16 As[128 * 64];
  __shared__ u16 Bs[128 * 64];

  const int tid = threadIdx.x;
  const int lane = tid & 63;
  const int wid = tid >> 6;
  const int wm = (wid >> 1) * 64;
  const int wn = (wid & 1) * 64;
  const int l16 = lane & 15;
  const int quad = lane >> 4;
  const int swz8 = (l16 & 7) * 8;

  const u16* aga[4];
  const u16* bga[4];
  u16* alds[4];
  u16* blds[4];
  const int lr = lane >> 3;
  const int g = (lane & 7) ^ (lr & 7);
  const int kcol = g * 8;
#pragma unroll
  for (int j = 0; j < 4; ++j) {
    int chunk = wid * 4 + j;
    int rowl = chunk * 8 + lr;
    int slot = sbase + rowl;
    if (slot >= lim) slot = sbase;
    aga[j] = hbuf + (size_t)slot * Hh + kcol;
    bga[j] = w2t + ((size_t)e * Dd + n0 + rowl) * Hh + kcol;
    alds[j] = As + chunk * 512;
    blds[j] = Bs + chunk * 512;
  }

  v4f acc[4][4];
#pragma unroll
  for (int i = 0; i < 4; ++i)
#pragma unroll
    for (int j = 0; j < 4; ++j) acc[i][j] = {0.f, 0.f, 0.f, 0.f};

  int rowAoff[4], rowBoff[4];
#pragma unroll
  for (int t_ = 0; t_ < 4; ++t_) {
    rowAoff[t_] = (wm + t_ * 16 + l16) * 64;
    rowBoff[t_] = (wn + t_ * 16 + l16) * 64;
  }

  for (int k0 = 0; k0 < Hh; k0 += 64) {
    __syncthreads();
#pragma unroll
    for (int j = 0; j < 4; ++j) gload_lds16(aga[j] + k0, alds[j]);
#pragma unroll
    for (int j = 0; j < 4; ++j) gload_lds16(bga[j] + k0, blds[j]);
    __syncthreads();

#pragma unroll
    for (int s = 0; s < 2; ++s) {
      int coff = ((s * 4 + quad) * 8) ^ swz8;
      v8s a[4], b[4];
#pragma unroll
      for (int mt = 0; mt < 4; ++mt)
        a[mt] = *reinterpret_cast<const v8s*>(&As[rowAoff[mt] + coff]);
#pragma unroll
      for (int nt = 0; nt < 4; ++nt)
        b[nt] = *reinterpret_cast<const v8s*>(&Bs[rowBoff[nt] + coff]);
#pragma unroll
      for (int mt = 0; mt < 4; ++mt)
#pragma unroll
        for (int nt = 0; nt < 4; ++nt)
          acc[mt][nt] = __builtin_amdgcn_mfma_f32_16x16x32_bf16(a[mt], b[nt], acc[mt][nt], 0, 0, 0);
    }
  }

  float b2v[4];
  int ng[4];
#pragma unroll
  for (int nt = 0; nt < 4; ++nt) {
    ng[nt] = n0 + wn + nt * 16 + l16;
    b2v[nt] = b2[(size_t)e * Dd + ng[nt]];
  }
#pragma unroll
  for (int mt = 0; mt < 4; ++mt) {
#pragma unroll
    for (int i = 0; i < 4; ++i) {
      int m = wm + mt * 16 + quad * 4 + i;
      if (sbase + m < lim) {
        size_t rowbase = (size_t)(sbase + m) * Dd;
#pragma unroll
        for (int nt = 0; nt < 4; ++nt)
          ybuf[rowbase + ng[nt]] = f2bf(acc[mt][nt][i] + b2v[nt]);
      }
    }
  }
}

// out[t] = w0 * y[slot0] + w1 * y[slot1]
__global__ __launch_bounds__(256) void combine_kernel(
    const u16* __restrict__ ybuf, const int* __restrict__ slotmap,
    const float* __restrict__ topkw, float* __restrict__ out) {
  int idx = blockIdx.x * 256 + threadIdx.x;
  int t = idx >> 7;
  int d0 = (idx & 127) * 8;
  int s0 = slotmap[2 * t], s1 = slotmap[2 * t + 1];
  float w0 = topkw[2 * t], w1 = topkw[2 * t + 1];
  uint4 ya = *reinterpret_cast<const uint4*>(ybuf + (size_t)s0 * Dd + d0);
  uint4 yb = *reinterpret_cast<const uint4*>(ybuf + (size_t)s1 * Dd + d0);
  float r[8];
  const unsigned* pa = &ya.x;
  const unsigned* pb = &yb.x;
#pragma unroll
  for (int j = 0; j < 4; ++j) {
    unsigned a = pa[j], b = pb[j];
    r[2 * j]     = w0 * bf2f((u16)(a & 0xffff)) + w1 * bf2f((u16)(b & 0xffff));
    r[2 * j + 1] = w0 * bf2f((u16)(a >> 16))    + w1 * bf2f((u16)(b >> 16));
  }
  float4* op = reinterpret_cast<float4*>(out + (size_t)t * Dd + d0);
  op[0] = make_float4(r[0], r[1], r[2], r[3]);
  op[1] = make_float4(r[4], r[5], r[6], r[7]);
}

extern "C" void kernel_launch(void* const* d_in, const int* in_sizes, int n_in,
                              void* d_out, int out_size, void* d_ws, size_t ws_size,
                              hipStream_t stream) {
  const float* x  = (const float*)d_in[0];
  const float* Wg = (const float*)d_in[2];
  const float* bg = (const float*)d_in[3];
  const float* W1 = (const float*)d_in[4];
  const float* b1 = (const float*)d_in[5];
  const float* W2 = (const float*)d_in[6];
  const float* b2 = (const float*)d_in[7];
  float* out = (float*)d_out;

  char* p = (char*)d_ws;
  auto take = [&](size_t bytes) {
    char* q = p;
    p += (bytes + 255) & ~(size_t)255;
    return q;
  };
  int*   offs       = (int*)take(64);
  int*   panelE     = (int*)take(1024);
  int*   panelB     = (int*)take(1024);
  int*   nPanels    = (int*)take(256);
  int*   topki      = (int*)take((size_t)Tn * 2 * sizeof(int));
  float* topkw      = (float*)take((size_t)Tn * 2 * sizeof(float));
  int*   rows       = (int*)take((size_t)Tn * 2 * sizeof(int));
  int*   slotmap    = (int*)take((size_t)Tn * 2 * sizeof(int));
  u16*   xb         = (u16*)take((size_t)Tn * Dd * 2);
  u16*   w1t        = (u16*)take((size_t)Ee * Dd * Hh * 2);
  u16*   w2t        = (u16*)take((size_t)Ee * Dd * Hh * 2);
  u16*   hbuf       = (u16*)take((size_t)Tn * 2 * Hh * 2);
  u16*   ybuf       = (u16*)take((size_t)Tn * 2 * Dd * 2);

  prep_kernel<<<10240, 256, 0, stream>>>(x, Wg, bg, topki, topkw, xb, W1, w1t, W2, w2t);
  sort_kernel<<<1, 512, 0, stream>>>(topki, offs, rows, slotmap, panelE, panelB, nPanels);
  gemm1_kernel<<<8 * 16 * MAXP, 256, 0, stream>>>(xb, w1t, b1, offs, rows,
                                                  panelE, panelB, nPanels, hbuf);
  gemm2_kernel<<<8 * 8 * MAXP, 256, 0, stream>>>(hbuf, w2t, b2, offs,
                                                 panelE, panelB, nPanels, ybuf);
  combine_kernel<<<(Tn * Dd / 8) / 256, 256, 0, stream>>>(ybuf, slotmap, topkw, out);
}

// Round 4
// 410.882 us; speedup vs baseline: 1.0821x; 1.0431x over previous
//
#include <hip/hip_runtime.h>

typedef unsigned short u16;
typedef short v8s __attribute__((ext_vector_type(8)));
typedef float v4f __attribute__((ext_vector_type(4)));
typedef u16 u16x8 __attribute__((ext_vector_type(8)));
typedef u16 u16x4 __attribute__((ext_vector_type(4)));

constexpr int Tn = 8192;   // tokens = B*S
constexpr int Dd = 1024;   // model dim
constexpr int Hh = 2048;   // hidden dim
constexpr int Ee = 8;      // experts
constexpr int MAXP = 17;   // ceil(max 128-row panels / 8); panels <= 128+8=136
constexpr int G1GEMM = 8 * 16 * MAXP;  // 2176 gemm1 blocks
constexpr int G1XTRA = 1024;           // W2-transpose rider blocks (4 tiles each)

// round-to-nearest-even f32 -> bf16 (inputs finite)
static __device__ __forceinline__ u16 f2bf(float v) {
  unsigned u = __float_as_uint(v);
  unsigned r = (u + 0x7fffu + ((u >> 16) & 1u)) >> 16;
  return (u16)r;
}

static __device__ __forceinline__ float bf2f(u16 v) {
  return __uint_as_float(((unsigned)v) << 16);
}

// async global -> LDS, 16B per lane; LDS dest = wave-uniform base + lane*16
static __device__ __forceinline__ void gload_lds16(const u16* g, u16* l) {
  __builtin_amdgcn_global_load_lds(
      (const __attribute__((address_space(1))) unsigned int*)g,
      (__attribute__((address_space(3))) unsigned int*)l, 16, 0, 0);
}

// ---------------------------------------------------------------------------
// hbuf / w2t K-PERMUTED LAYOUT:
// Within each 64-wide k-group, stored position p = l16*4 + nt holds the value
// for actual column c = nt*16 + l16. gemm1's C-fragment packs each lane's 4
// outputs into one contiguous ushort4 store; gemm2 consumes hbuf/w2t through
// 64-aligned 16B k-chunks + an order-invariant MFMA k-sum, so w2t's Hh index
// is permuted identically at transpose time and gemm2's core is unchanged.
//
// ybuf TOKEN-MAJOR LAYOUT (R4): gemm2 scatters each output row to
// ybuf[idx = token*2 + choice]. Store-segment count is unchanged (rows were
// already 2KB apart); combine becomes a pure streaming add with no slotmap.
// ---------------------------------------------------------------------------

// 64x64 transpose+cvt tile worker (256 threads). Caller owns syncs between
// successive calls on the same tile buffer.
static __device__ __forceinline__ void transpose_tile64(
    const float* __restrict__ ip, u16* __restrict__ op,
    int R, int C, int r0, int c0, bool permute, float (*tile)[65]) {
  int tid = threadIdx.x;
#pragma unroll
  for (int k = 0; k < 4; ++k) {
    int f = k * 256 + tid;
    int r = f >> 4, c4 = (f & 15) * 4;
    float4 v = *reinterpret_cast<const float4*>(ip + (size_t)(r0 + r) * C + c0 + c4);
    tile[r][c4] = v.x; tile[r][c4 + 1] = v.y; tile[r][c4 + 2] = v.z; tile[r][c4 + 3] = v.w;
  }
  __syncthreads();
  int j = tid & 7;
#pragma unroll
  for (int rr = 0; rr < 2; ++rr) {
    int oc = (tid >> 3) + rr * 32;
    u16x8 o;
    if (!permute) {
#pragma unroll
      for (int q = 0; q < 8; ++q) o[q] = f2bf(tile[j * 8 + q][oc]);
    } else {
      // permuted: stored p holds actual input-row (p&3)*16 + (p>>2)
#pragma unroll
      for (int q = 0; q < 8; ++q) {
        int p_ = j * 8 + q;
        int src = (p_ & 3) * 16 + (p_ >> 2);
        o[q] = f2bf(tile[src][oc]);
      }
    }
    *reinterpret_cast<u16x8*>(op + (size_t)(c0 + oc) * R + r0 + j * 8) = o;
  }
}

// PREP (fused): blocks [0,4096) = W1 transpose+cvt, blocks [4096,6144) =
// gating (+x->bf16). Gating LAST so xb is L2-warm when gemm1's A-gathers
// start (R3 post-mortem: cold xb cost gemm1 ~11 µs of gather latency on the
// barrier-drain critical path). W2's transpose rides inside gemm1's dispatch.
__global__ __launch_bounds__(256) void prep_kernel(
    const float* __restrict__ x, const float* __restrict__ Wg, const float* __restrict__ bg,
    int* __restrict__ topki, float* __restrict__ topkw, u16* __restrict__ xb,
    const float* __restrict__ W1, u16* __restrict__ w1t) {
  __shared__ float tile[64][65];
  int blk = blockIdx.x;

  if (blk < 4096) {
    // ------- W1 [E][Dd][Hh] -> w1t [E][Hh][Dd], 32 x 16 tiles per expert ----
    int e = blk >> 9;
    int t = blk & 511;
    int cx = t & 31, cy = t >> 5;
    const float* ip = W1 + (size_t)e * Dd * Hh;
    u16* op = w1t + (size_t)e * Dd * Hh;
    transpose_tile64(ip, op, Dd, Hh, cy * 64, cx * 64, false, tile);
    return;
  }

  // ---------------- gating: one wave per token ----------------
  int lane = threadIdx.x & 63;
  int t = (blk - 4096) * 4 + (threadIdx.x >> 6);
  const float4* xr = reinterpret_cast<const float4*>(x + (size_t)t * Dd);
  float acc[8] = {0.f, 0.f, 0.f, 0.f, 0.f, 0.f, 0.f, 0.f};
#pragma unroll
  for (int it = 0; it < 4; ++it) {
    float4 xv = xr[it * 64 + lane];
    int r = it * 256 + lane * 4;
    ushort4 o;
    o.x = f2bf(xv.x); o.y = f2bf(xv.y); o.z = f2bf(xv.z); o.w = f2bf(xv.w);
    *reinterpret_cast<ushort4*>(xb + (size_t)t * Dd + r) = o;
    const float4* wr = reinterpret_cast<const float4*>(Wg + (size_t)r * 8);
    float xs[4] = {xv.x, xv.y, xv.z, xv.w};
#pragma unroll
    for (int q = 0; q < 4; ++q) {
      float4 a = wr[q * 2], b = wr[q * 2 + 1];
      acc[0] += xs[q] * a.x; acc[1] += xs[q] * a.y; acc[2] += xs[q] * a.z; acc[3] += xs[q] * a.w;
      acc[4] += xs[q] * b.x; acc[5] += xs[q] * b.y; acc[6] += xs[q] * b.z; acc[7] += xs[q] * b.w;
    }
  }
#pragma unroll
  for (int e = 0; e < 8; ++e) {
#pragma unroll
    for (int off = 32; off > 0; off >>= 1) acc[e] += __shfl_xor(acc[e], off, 64);
  }
  if (lane == 0) {
    float l[8];
    float mx = -1e30f;
#pragma unroll
    for (int e = 0; e < 8; ++e) { l[e] = acc[e] + bg[e]; mx = fmaxf(mx, l[e]); }
    int i0 = 0;
#pragma unroll
    for (int e = 1; e < 8; ++e) if (l[e] > l[i0]) i0 = e;
    int i1 = (i0 == 0) ? 1 : 0;
#pragma unroll
    for (int e = 0; e < 8; ++e) if (e != i0 && l[e] > l[i1]) i1 = e;
    float e0 = __expf(l[i0] - mx), e1 = __expf(l[i1] - mx);
    float inv = 1.0f / (e0 + e1);
    topki[2 * t] = i0; topki[2 * t + 1] = i1;
    topkw[2 * t] = e0 * inv; topkw[2 * t + 1] = e1 * inv;
  }
}

// SORT (fused hist+prefix+scatter): ONE block, 512 threads, no atomics.
// rows[slot] = idx (= token*2 + choice); gemm1 uses idx>>1 for the xb gather,
// gemm2 uses idx for the token-major ybuf scatter. No slotmap.
__global__ __launch_bounds__(512) void sort_kernel(
    const int* __restrict__ topki,
    int* __restrict__ offs, int* __restrict__ rows,
    int* __restrict__ panelE, int* __restrict__ panelB, int* __restrict__ nPanels) {
  __shared__ int scan[8][512];   // counts -> exclusive within-expert prefixes
  __shared__ int tot_l[8];
  __shared__ int offs_l[9];
  const int tt = threadIdx.x;    // 0..511
  const int base = tt * 32;      // 512*32 = 16384 = Tn*2 entries

  // phase A
  int ev[32];
  int cnt[8] = {0, 0, 0, 0, 0, 0, 0, 0};
#pragma unroll
  for (int jj = 0; jj < 32; ++jj) {
    int e = topki[base + jj];
    ev[jj] = e;
#pragma unroll
    for (int q = 0; q < 8; ++q) cnt[q] += (e == q) ? 1 : 0;
  }
#pragma unroll
  for (int q = 0; q < 8; ++q) scan[q][tt] = cnt[q];
  __syncthreads();

  // phase B: wave w scans expert row w
  {
    int w = tt >> 6, l = tt & 63;
    int v[8];
    int s = 0;
#pragma unroll
    for (int jj = 0; jj < 8; ++jj) { v[jj] = scan[w][l * 8 + jj]; s += v[jj]; }
    int si = s;
#pragma unroll
    for (int off = 1; off < 64; off <<= 1) {
      int o = __shfl_up(si, off, 64);
      if (l >= off) si += o;
    }
    int run = si - s;  // exclusive base for this lane's 8 threads
#pragma unroll
    for (int jj = 0; jj < 8; ++jj) { scan[w][l * 8 + jj] = run; run += v[jj]; }
    if (l == 63) tot_l[w] = si;
  }
  __syncthreads();

  if (tt == 0) {
    int o = 0;
#pragma unroll
    for (int e = 0; e < 8; ++e) { offs_l[e] = o; o += tot_l[e]; }
    offs_l[8] = o;
#pragma unroll
    for (int e = 0; e < 9; ++e) offs[e] = offs_l[e];
    int np = 0;
    for (int e = 0; e < 8; ++e) {
      for (int m0 = 0; m0 < tot_l[e]; m0 += 128) {
        panelE[np] = e;
        panelB[np] = offs_l[e] + m0;
        ++np;
      }
    }
    *nPanels = np;
  }
  __syncthreads();

  // phase C: slot assignment (scan[e][tt] is this thread's private cursor)
#pragma unroll
  for (int jj = 0; jj < 32; ++jj) {
    int e = ev[jj];
    int idx = base + jj;
    int slot = scan[e][tt]++ + offs_l[e];
    rows[slot] = idx;                    // full idx = token*2 + choice
  }
}

// ---- GEMM cores: 128x128 tile, BK=64, XOR-swizzled LDS (R1 config: proven) ----
// R2 post-mortem: 8-wave/512-thr split raised occupancy 27->38% but CUT
// MfmaUtil 30->25% — per-wave compute depth between barriers matters more
// than wave count in this lockstep 2-barrier structure. (256,2) / 4 waves /
// acc 4x4 is the structural optimum for this geometry.

// GEMM1: h[slot][P(n)] = gelu( x[idx>>1] @ W1[e] + b1[e] )  (k-permuted store)
// Rider blocks [G1GEMM, G1GEMM+G1XTRA): W2 [E][Hh][Dd] -> w2t (permuted),
// 4 tiles each — W2T is only needed by gemm2 (next launch), so it hides in
// gemm1's scheduling slack instead of serializing inside prep.
__global__ __launch_bounds__(256, 2) void gemm1_kernel(
    const u16* __restrict__ xb, const u16* __restrict__ w1t, const float* __restrict__ b1,
    const int* __restrict__ offs, const int* __restrict__ rows,
    const int* __restrict__ panelE, const int* __restrict__ panelB,
    const int* __restrict__ nPanels, u16* __restrict__ hbuf,
    const float* __restrict__ W2, u16* __restrict__ w2t) {
  __shared__ __align__(16) u16 smem[2 * 128 * 64];   // 32 KB: As|Bs, or f32 tile
  u16* As = smem;
  u16* Bs = smem + 128 * 64;

  const int bid = blockIdx.x;
  if (bid >= G1GEMM) {
    // ---- W2 transpose rider: 4 of 4096 64x64 tiles ----
    float (*tile)[65] = reinterpret_cast<float (*)[65]>(smem);
    int tb = bid - G1GEMM;
#pragma unroll 1
    for (int s = 0; s < 4; ++s) {
      int tileid = tb * 4 + s;
      int e = tileid >> 9;
      int t = tileid & 511;
      int cx = t & 15, cy = t >> 4;     // 16 col-tiles (Dd), 32 row-tiles (Hh)
      if (s) __syncthreads();
      transpose_tile64(W2 + (size_t)e * Dd * Hh, w2t + (size_t)e * Dd * Hh,
                       Hh, Dd, cy * 64, cx * 64, true, tile);
    }
    return;
  }

  const int xcd = bid & 7;
  const int q = bid >> 3;
  const int n = q & 15;               // Hh/128 = 16 n-blocks
  const int pi = (q >> 4) * 8 + xcd;
  if (pi >= *nPanels) return;
  const int e = panelE[pi];
  const int sbase = panelB[pi];
  const int lim = offs[e + 1];
  const int n0 = n * 128;

  const int tid = threadIdx.x;
  const int lane = tid & 63;
  const int wid = tid >> 6;
  const int wm = (wid >> 1) * 64;
  const int wn = (wid & 1) * 64;
  const int l16 = lane & 15;
  const int quad = lane >> 4;
  const int swz8 = (l16 & 7) * 8;     // read-side XOR mask (elems)

  const u16* aga[4];
  const u16* bga[4];
  u16* alds[4];
  u16* blds[4];
  const int lr = lane >> 3;                 // row within 8-row chunk
  const int g = (lane & 7) ^ (lr & 7);      // staged global k-chunk (XOR swizzle)
  const int kcol = g * 8;
#pragma unroll
  for (int j = 0; j < 4; ++j) {
    int chunk = wid * 4 + j;                // 0..15 covers rows [chunk*8, chunk*8+8)
    int rowl = chunk * 8 + lr;
    int slot = sbase + rowl;
    if (slot >= lim) slot = sbase;
    aga[j] = xb + (size_t)(rows[slot] >> 1) * Dd + kcol;
    bga[j] = w1t + ((size_t)e * Hh + n0 + rowl) * Dd + kcol;
    alds[j] = As + chunk * 512;             // 1 KB per wave-instruction
    blds[j] = Bs + chunk * 512;
  }

  v4f acc[4][4];
#pragma unroll
  for (int i = 0; i < 4; ++i)
#pragma unroll
    for (int j = 0; j < 4; ++j) acc[i][j] = {0.f, 0.f, 0.f, 0.f};

  int rowAoff[4], rowBoff[4];
#pragma unroll
  for (int t_ = 0; t_ < 4; ++t_) {
    rowAoff[t_] = (wm + t_ * 16 + l16) * 64;
    rowBoff[t_] = (wn + t_ * 16 + l16) * 64;
  }

  for (int k0 = 0; k0 < Dd; k0 += 64) {
    __syncthreads();
#pragma unroll
    for (int j = 0; j < 4; ++j) gload_lds16(aga[j] + k0, alds[j]);
#pragma unroll
    for (int j = 0; j < 4; ++j) gload_lds16(bga[j] + k0, blds[j]);
    __syncthreads();

#pragma unroll
    for (int s = 0; s < 2; ++s) {
      int coff = ((s * 4 + quad) * 8) ^ swz8;
      v8s a[4], b[4];
#pragma unroll
      for (int mt = 0; mt < 4; ++mt)
        a[mt] = *reinterpret_cast<const v8s*>(&As[rowAoff[mt] + coff]);
#pragma unroll
      for (int nt = 0; nt < 4; ++nt)
        b[nt] = *reinterpret_cast<const v8s*>(&Bs[rowBoff[nt] + coff]);
#pragma unroll
      for (int mt = 0; mt < 4; ++mt)
#pragma unroll
        for (int nt = 0; nt < 4; ++nt)
          acc[mt][nt] = __builtin_amdgcn_mfma_f32_16x16x32_bf16(a[mt], b[nt], acc[mt][nt], 0, 0, 0);
    }
  }

  // epilogue: bias + gelu, PACKED 8B stores into k-permuted hbuf.
  float b1v[4];
  const int ngbase = n0 + wn;           // 64-aligned group base
#pragma unroll
  for (int nt = 0; nt < 4; ++nt) b1v[nt] = b1[(size_t)e * Hh + ngbase + nt * 16 + l16];
#pragma unroll
  for (int mt = 0; mt < 4; ++mt) {
#pragma unroll
    for (int i = 0; i < 4; ++i) {
      int m = wm + mt * 16 + quad * 4 + i;
      if (sbase + m < lim) {
        u16x4 o;
#pragma unroll
        for (int nt = 0; nt < 4; ++nt) {
          float v = acc[mt][nt][i] + b1v[nt];
          float s = 1.0f / (1.0f + __expf(-1.5957691216057308f * (v + 0.044715f * v * v * v)));
          o[nt] = f2bf(v * s);
        }
        *reinterpret_cast<u16x4*>(hbuf + (size_t)(sbase + m) * Hh + ngbase + l16 * 4) = o;
      }
    }
  }
}

// GEMM2: ybuf[rows[slot]][n] = h[slot] @ W2[e] + b2[e]   (token-major scatter)
__global__ __launch_bounds__(256, 2) void gemm2_kernel(
    const u16* __restrict__ hbuf, const u16* __restrict__ w2t, const float* __restrict__ b2,
    const int* __restrict__ offs, const int* __restrict__ rows,
    const int* __restrict__ panelE, const int* __restrict__ panelB,
    const int* __restrict__ nPanels, u16* __restrict__ ybuf) {
  const int bid = blockIdx.x;
  const int xcd = bid & 7;
  const int q = bid >> 3;
  const int n = q & 7;                // Dd/128 = 8 n-blocks
  const int pi = (q >> 3) * 8 + xcd;
  if (pi >= *nPanels) return;
  const int e = panelE[pi];
  const int sbase = panelB[pi];
  const int lim = offs[e + 1];
  const int n0 = n * 128;

  __shared__ __align__(16) u16 smem[2 * 128 * 64];
  u16* As = smem;
  u16* Bs = smem + 128 * 64;

  const int tid = threadIdx.x;
  const int lane = tid & 63;
  const int wid = tid >> 6;
  const int wm = (wid >> 1) * 64;
  const int wn = (wid & 1) * 64;
  const int l16 = lane & 15;
  const int quad = lane >> 4;
  const int swz8 = (l16 & 7) * 8;

  const u16* aga[4];
  const u16* bga[4];
  u16* alds[4];
  u16* blds[4];
  const int lr = lane >> 3;
  const int g = (lane & 7) ^ (lr & 7);
  const int kcol = g * 8;
#pragma unroll
  for (int j = 0; j < 4; ++j) {
    int chunk = wid * 4 + j;
    int rowl = chunk * 8 + lr;
    int slot = sbase + rowl;
    if (slot >= lim) slot = sbase;
    aga[j] = hbuf + (size_t)slot * Hh + kcol;
    bga[j] = w2t + ((size_t)e * Dd + n0 + rowl) * Hh + kcol;
    alds[j] = As + chunk * 512;
    blds[j] = Bs + chunk * 512;
  }

  v4f acc[4][4];
#pragma unroll
  for (int i = 0; i < 4; ++i)
#pragma unroll
    for (int j = 0; j < 4; ++j) acc[i][j] = {0.f, 0.f, 0.f, 0.f};

  int rowAoff[4], rowBoff[4];
#pragma unroll
  for (int t_ = 0; t_ < 4; ++t_) {
    rowAoff[t_] = (wm + t_ * 16 + l16) * 64;
    rowBoff[t_] = (wn + t_ * 16 + l16) * 64;
  }

  for (int k0 = 0; k0 < Hh; k0 += 64) {
    __syncthreads();
#pragma unroll
    for (int j = 0; j < 4; ++j) gload_lds16(aga[j] + k0, alds[j]);
#pragma unroll
    for (int j = 0; j < 4; ++j) gload_lds16(bga[j] + k0, blds[j]);
    __syncthreads();

#pragma unroll
    for (int s = 0; s < 2; ++s) {
      int coff = ((s * 4 + quad) * 8) ^ swz8;
      v8s a[4], b[4];
#pragma unroll
      for (int mt = 0; mt < 4; ++mt)
        a[mt] = *reinterpret_cast<const v8s*>(&As[rowAoff[mt] + coff]);
#pragma unroll
      for (int nt = 0; nt < 4; ++nt)
        b[nt] = *reinterpret_cast<const v8s*>(&Bs[rowBoff[nt] + coff]);
#pragma unroll
      for (int mt = 0; mt < 4; ++mt)
#pragma unroll
        for (int nt = 0; nt < 4; ++nt)
          acc[mt][nt] = __builtin_amdgcn_mfma_f32_16x16x32_bf16(a[mt], b[nt], acc[mt][nt], 0, 0, 0);
    }
  }

  float b2v[4];
  int ng[4];
#pragma unroll
  for (int nt = 0; nt < 4; ++nt) {
    ng[nt] = n0 + wn + nt * 16 + l16;
    b2v[nt] = b2[(size_t)e * Dd + ng[nt]];
  }
#pragma unroll
  for (int mt = 0; mt < 4; ++mt) {
#pragma unroll
    for (int i = 0; i < 4; ++i) {
      int m = wm + mt * 16 + quad * 4 + i;
      if (sbase + m < lim) {
        size_t rowbase = (size_t)rows[sbase + m] * Dd;   // token-major scatter
#pragma unroll
        for (int nt = 0; nt < 4; ++nt)
          ybuf[rowbase + ng[nt]] = f2bf(acc[mt][nt][i] + b2v[nt]);
      }
    }
  }
}

// out[t] = w0 * ybuf[2t] + w1 * ybuf[2t+1]  (pure streaming, no indirection)
__global__ __launch_bounds__(256) void combine_kernel(
    const u16* __restrict__ ybuf, const float* __restrict__ topkw,
    float* __restrict__ out) {
  int idx = blockIdx.x * 256 + threadIdx.x;
  int t = idx >> 7;
  int d0 = (idx & 127) * 8;
  float w0 = topkw[2 * t], w1 = topkw[2 * t + 1];
  uint4 ya = *reinterpret_cast<const uint4*>(ybuf + (size_t)(2 * t) * Dd + d0);
  uint4 yb = *reinterpret_cast<const uint4*>(ybuf + (size_t)(2 * t + 1) * Dd + d0);
  float r[8];
  const unsigned* pa = &ya.x;
  const unsigned* pb = &yb.x;
#pragma unroll
  for (int j = 0; j < 4; ++j) {
    unsigned a = pa[j], b = pb[j];
    r[2 * j]     = w0 * bf2f((u16)(a & 0xffff)) + w1 * bf2f((u16)(b & 0xffff));
    r[2 * j + 1] = w0 * bf2f((u16)(a >> 16))    + w1 * bf2f((u16)(b >> 16));
  }
  float4* op = reinterpret_cast<float4*>(out + (size_t)t * Dd + d0);
  op[0] = make_float4(r[0], r[1], r[2], r[3]);
  op[1] = make_float4(r[4], r[5], r[6], r[7]);
}

extern "C" void kernel_launch(void* const* d_in, const int* in_sizes, int n_in,
                              void* d_out, int out_size, void* d_ws, size_t ws_size,
                              hipStream_t stream) {
  const float* x  = (const float*)d_in[0];
  const float* Wg = (const float*)d_in[2];
  const float* bg = (const float*)d_in[3];
  const float* W1 = (const float*)d_in[4];
  const float* b1 = (const float*)d_in[5];
  const float* W2 = (const float*)d_in[6];
  const float* b2 = (const float*)d_in[7];
  float* out = (float*)d_out;

  char* p = (char*)d_ws;
  auto take = [&](size_t bytes) {
    char* q = p;
    p += (bytes + 255) & ~(size_t)255;
    return q;
  };
  int*   offs       = (int*)take(64);
  int*   panelE     = (int*)take(1024);
  int*   panelB     = (int*)take(1024);
  int*   nPanels    = (int*)take(256);
  int*   topki      = (int*)take((size_t)Tn * 2 * sizeof(int));
  float* topkw      = (float*)take((size_t)Tn * 2 * sizeof(float));
  int*   rows       = (int*)take((size_t)Tn * 2 * sizeof(int));
  u16*   xb         = (u16*)take((size_t)Tn * Dd * 2);
  u16*   w1t        = (u16*)take((size_t)Ee * Dd * Hh * 2);
  u16*   w2t        = (u16*)take((size_t)Ee * Dd * Hh * 2);
  u16*   hbuf       = (u16*)take((size_t)Tn * 2 * Hh * 2);
  u16*   ybuf       = (u16*)take((size_t)Tn * 2 * Dd * 2);

  prep_kernel<<<6144, 256, 0, stream>>>(x, Wg, bg, topki, topkw, xb, W1, w1t);
  sort_kernel<<<1, 512, 0, stream>>>(topki, offs, rows, panelE, panelB, nPanels);
  gemm1_kernel<<<G1GEMM + G1XTRA, 256, 0, stream>>>(xb, w1t, b1, offs, rows,
                                                    panelE, panelB, nPanels, hbuf,
                                                    W2, w2t);
  gemm2_kernel<<<8 * 8 * MAXP, 256, 0, stream>>>(hbuf, w2t, b2, offs, rows,
                                                 panelE, panelB, nPanels, ybuf);
  combine_kernel<<<(Tn * Dd / 8) / 256, 256, 0, stream>>>(ybuf, topkw, out);
}